// Round 13
// baseline (207.125 us; speedup 1.0000x reference)
//
#include <hip/hip_runtime.h>
#include <hip/hip_bf16.h>

typedef short bf16x8 __attribute__((ext_vector_type(8)));
typedef float f32x4 __attribute__((ext_vector_type(4)));
typedef unsigned uint2v __attribute__((ext_vector_type(2)));

#define MFMA16(a, b, c) __builtin_amdgcn_mfma_f32_16x16x32_bf16((a), (b), (c), 0, 0, 0)

#if __has_builtin(__builtin_amdgcn_exp2f)
#define EXP2(x) __builtin_amdgcn_exp2f(x)
#else
#define EXP2(x) exp2f(x)
#endif

static constexpr int B_ = 2, S_ = 2048, D_ = 1024, H_ = 16, DH = 64;
static constexpr int M_ = B_ * S_;   // 4096
static constexpr int K_ = D_;        // 1024
static constexpr float kQS = 0.18033688011112042f;   // log2(e)/8, folded into Wq

static __device__ __forceinline__ ushort f2bf(float f) {
    __hip_bfloat16 h = __float2bfloat16(f);
    return *reinterpret_cast<ushort*>(&h);
}

static __device__ __forceinline__ void gload16(const ushort* g, ushort* l) {
    __builtin_amdgcn_global_load_lds((const __attribute__((address_space(1))) void*)g,
                                     (__attribute__((address_space(3))) void*)l, 16, 0, 0);
}

// pack two fp32 -> (bf16(hi) << 16) | bf16(lo), truncation (v_perm_b32)
static __device__ __forceinline__ unsigned pkbf(float lo, float hi) {
    return __builtin_amdgcn_perm(__builtin_bit_cast(unsigned, hi),
                                 __builtin_bit_cast(unsigned, lo), 0x07060302u);
}

// ---------------------------------------------------------------------------
// Prep: z=0..3 -> fused convert+transpose of the 4 weights (Wq pre-scaled by
// log2(e)/8); z=4 -> fp32->bf16 convert of x (4M elems, 16/thread).
// ---------------------------------------------------------------------------
__global__ __launch_bounds__(256) void prep5(const float* __restrict__ x,
                                             const float* __restrict__ W0,
                                             const float* __restrict__ W1,
                                             const float* __restrict__ W2,
                                             const float* __restrict__ W3,
                                             ushort* __restrict__ xb,
                                             ushort* __restrict__ T0,
                                             ushort* __restrict__ T1,
                                             ushort* __restrict__ T2,
                                             ushort* __restrict__ T3) {
    int z = blockIdx.z;
    int tx = threadIdx.x, ty = threadIdx.y;
    int t = ty * 32 + tx;
    if (z == 4) {
        int blk = blockIdx.y * 32 + blockIdx.x;      // 0..1023
#pragma unroll
        for (int k = 0; k < 4; k++) {
            int i = blk * 1024 + k * 256 + t;        // float4 id
            float4 v = reinterpret_cast<const float4*>(x)[i];
            ushort4 o;
            o.x = f2bf(v.x); o.y = f2bf(v.y); o.z = f2bf(v.z); o.w = f2bf(v.w);
            reinterpret_cast<ushort4*>(xb)[i] = o;
        }
        return;
    }
    __shared__ float tile[32][33];
    const float* W = (z == 0) ? W0 : (z == 1) ? W1 : (z == 2) ? W2 : W3;
    ushort* T = (z == 0) ? T0 : (z == 1) ? T1 : (z == 2) ? T2 : T3;
    float sc = (z == 0) ? kQS : 1.0f;
    int bx = blockIdx.x, by = blockIdx.y;
#pragma unroll
    for (int i = 0; i < 4; i++)
        tile[ty + i * 8][tx] = W[(by * 32 + ty + i * 8) * D_ + bx * 32 + tx];
    __syncthreads();
#pragma unroll
    for (int i = 0; i < 4; i++)
        T[(bx * 32 + ty + i * 8) * K_ + by * 32 + tx] = f2bf(tile[tx][ty + i * 8] * sc);
}

// ---------------------------------------------------------------------------
// m97-style GEMM (single-buffered: r12 proved dbuf neutral here).
// Block tile 128 x TN, 4 waves (2x2), wave tile 64 x (TN/2).
// OPERAND-SWAPPED MFMA (r11 trick) for Q/K and O-proj blocks: D-layout gives
// each lane 4 CONSECUTIVE columns -> ushort4/float4 epilogue stores
// (64 scalar 2B -> 16x8B for Q/K; 32 scalar 4B -> 8x16B for O-proj).
// V blocks keep the unswapped order (ushort4-along-s V^T pack).
// MODE 0 (TN=128): fused QKV (N=3072); MODE 1 (TN=64): O-proj fp32 + bias.
// ---------------------------------------------------------------------------
template <int MODE, int TN>
__global__ __launch_bounds__(256, 3) void gemm128(const ushort* __restrict__ A,
                                                  const ushort* __restrict__ Wt,
                                                  const float* __restrict__ bias_q,
                                                  const float* __restrict__ bias_k,
                                                  const float* __restrict__ bias_v,
                                                  ushort* __restrict__ Qb,
                                                  ushort* __restrict__ Kb,
                                                  ushort* __restrict__ Vtb,
                                                  float* __restrict__ outf) {
    constexpr int NJ = TN / 32;
    __shared__ __align__(16) ushort As[128 * 32];
    __shared__ __align__(16) ushort Bs[TN * 32];

    int m0 = blockIdx.x * 128;
    int n0 = blockIdx.y * TN;
    int t = threadIdx.x;
    int lane = t & 63, w = t >> 6;
    int ln = lane & 15, lq = lane >> 4;
    int wm = (w >> 1) * 64, wn = (w & 1) * (TN / 2);

    int c0 = t, c1 = t + 256;
    const ushort* Ag0 = A + (size_t)(m0 + (c0 >> 2)) * K_ + (c0 & 3) * 8;
    const ushort* Ag1 = A + (size_t)(m0 + (c1 >> 2)) * K_ + (c1 & 3) * 8;
    const ushort* Bg0 = Wt + (size_t)(n0 + (c0 >> 2)) * K_ + (c0 & 3) * 8;
    const ushort* Bg1 = Wt + (size_t)(n0 + (c1 >> 2)) * K_ + (c1 & 3) * 8;
    ushort* Al0 = As + c0 * 8;
    ushort* Al1 = As + c1 * 8;
    ushort* Bl0 = Bs + c0 * 8;
    ushort* Bl1 = Bs + c1 * 8;

    const bool swp = (MODE == 1) || (n0 < 2048);   // block-uniform

    f32x4 acc[4][NJ];
#pragma unroll
    for (int i = 0; i < 4; i++)
#pragma unroll
        for (int j = 0; j < NJ; j++) acc[i][j] = f32x4{0.f, 0.f, 0.f, 0.f};

    if (swp) {
        for (int k0 = 0; k0 < K_; k0 += 32) {
            gload16(Ag0 + k0, Al0);
            gload16(Ag1 + k0, Al1);
            gload16(Bg0 + k0, Bl0);
            if (TN == 128) gload16(Bg1 + k0, Bl1);
            __syncthreads();
            bf16x8 af[4], bfr[NJ];
#pragma unroll
            for (int i = 0; i < 4; i++)
                af[i] = *reinterpret_cast<const bf16x8*>(As + (wm + i * 16 + ln) * 32 + lq * 8);
#pragma unroll
            for (int j = 0; j < NJ; j++)
                bfr[j] = *reinterpret_cast<const bf16x8*>(Bs + (wn + j * 16 + ln) * 32 + lq * 8);
#pragma unroll
            for (int i = 0; i < 4; i++)
#pragma unroll
                for (int j = 0; j < NJ; j++)
                    acc[i][j] = MFMA16(bfr[j], af[i], acc[i][j]);   // swapped
            __syncthreads();
        }
    } else {
        for (int k0 = 0; k0 < K_; k0 += 32) {
            gload16(Ag0 + k0, Al0);
            gload16(Ag1 + k0, Al1);
            gload16(Bg0 + k0, Bl0);
            if (TN == 128) gload16(Bg1 + k0, Bl1);
            __syncthreads();
            bf16x8 af[4], bfr[NJ];
#pragma unroll
            for (int i = 0; i < 4; i++)
                af[i] = *reinterpret_cast<const bf16x8*>(As + (wm + i * 16 + ln) * 32 + lq * 8);
#pragma unroll
            for (int j = 0; j < NJ; j++)
                bfr[j] = *reinterpret_cast<const bf16x8*>(Bs + (wn + j * 16 + ln) * 32 + lq * 8);
#pragma unroll
            for (int i = 0; i < 4; i++)
#pragma unroll
                for (int j = 0; j < NJ; j++)
                    acc[i][j] = MFMA16(af[i], bfr[j], acc[i][j]);
            __syncthreads();
        }
    }

    if (MODE == 1) {
        // swapped: lane owns m = ...+ln, 4 consecutive n -> float4 stores
#pragma unroll
        for (int j = 0; j < NJ; j++) {
            int nb = n0 + wn + j * 16 + lq * 4;
            float4 bv4 = *reinterpret_cast<const float4*>(bias_q + nb);
#pragma unroll
            for (int i = 0; i < 4; i++) {
                int m = m0 + wm + i * 16 + ln;
                float4 o;
                o.x = acc[i][j][0] + bv4.x;
                o.y = acc[i][j][1] + bv4.y;
                o.z = acc[i][j][2] + bv4.z;
                o.w = acc[i][j][3] + bv4.w;
                *reinterpret_cast<float4*>(outf + (size_t)m * D_ + nb) = o;
            }
        }
    } else if (n0 < 2048) {
        // swapped Q/K: 4 consecutive dh -> ushort4 stores into [B,H,S,Dh]
        int which = n0 >> 10;
        const float* bp = which ? bias_k : bias_q;
        ushort* dst = which ? Kb : Qb;
        float bsc = which ? 1.0f : kQS;
#pragma unroll
        for (int j = 0; j < NJ; j++) {
            int nb = ((n0 + wn + j * 16) & 1023) + lq * 4;
            int h = nb >> 6, dhb = nb & 63;
            float4 bv4 = *reinterpret_cast<const float4*>(bp + nb);
            bv4.x *= bsc; bv4.y *= bsc; bv4.z *= bsc; bv4.w *= bsc;
#pragma unroll
            for (int i = 0; i < 4; i++) {
                int m = m0 + wm + i * 16 + ln;
                int b = m >> 11, s = m & 2047;
                ushort4 o4;
                o4.x = f2bf(acc[i][j][0] + bv4.x);
                o4.y = f2bf(acc[i][j][1] + bv4.y);
                o4.z = f2bf(acc[i][j][2] + bv4.z);
                o4.w = f2bf(acc[i][j][3] + bv4.w);
                *reinterpret_cast<ushort4*>(dst + (((size_t)(b * H_ + h) * S_) + s) * DH + dhb) = o4;
            }
        }
    } else {
        // V (unswapped): per lane 4 consecutive s -> ushort4 into [B,H,Dh,S]
#pragma unroll
        for (int j = 0; j < NJ; j++) {
            int n = n0 + wn + j * 16 + ln;
            int nn = n & 1023, h = nn >> 6, dh = nn & 63;
            float bv = bias_v[nn];
#pragma unroll
            for (int i = 0; i < 4; i++) {
                int m = m0 + wm + i * 16 + lq * 4;
                int b = m >> 11, s0 = m & 2047;
                ushort4 o4;
                o4.x = f2bf(acc[i][j][0] + bv);
                o4.y = f2bf(acc[i][j][1] + bv);
                o4.z = f2bf(acc[i][j][2] + bv);
                o4.w = f2bf(acc[i][j][3] + bv);
                *reinterpret_cast<ushort4*>(Vtb + (((size_t)(b * H_ + h) * DH) + dh) * S_ + s0) = o4;
            }
        }
    }
}

// ---------------------------------------------------------------------------
// Flash attention (r11 best, FROZEN): S^T = K·Q^T operand swap -> P packed
// with one ds_write_b64 per key-tile; l = ones-column MFMA of truncated P;
// 64-key tiles single-buffered, 2 barriers/iter, grid 1024 (4 blocks/CU).
// ---------------------------------------------------------------------------
__global__ __launch_bounds__(256) void attn64t(const ushort* __restrict__ Q,
                                               const ushort* __restrict__ K,
                                               const ushort* __restrict__ Vt,
                                               ushort* __restrict__ O) {
    __shared__ __align__(16) ushort Kl[512 * 8];      // 8 KB
    __shared__ __align__(16) ushort Vl[512 * 8];      // 8 KB
    __shared__ __align__(16) ushort Pl[4][16 * 72];   // 9 KB, pad->72

    int bid = blockIdx.x;
    int qb = bid & 31;         // 32 q-blocks of 64 rows
    int bh = bid >> 5;         // b*H + h
    int t = threadIdx.x;
    int lane = t & 63, w = t >> 6;
    int ln = lane & 15, lq = lane >> 4;
    int qt = qb * 4 + w;       // 16-row q tile per wave

    const ushort* Qp = Q + (size_t)bh * S_ * DH;
    const ushort* Kp = K + (size_t)bh * S_ * DH;
    const ushort* Vp = Vt + (size_t)bh * DH * S_;

    bf16x8 qf0 = *reinterpret_cast<const bf16x8*>(Qp + (qt * 16 + ln) * DH + lq * 8);
    bf16x8 qf1 = *reinterpret_cast<const bf16x8*>(Qp + (qt * 16 + ln) * DH + 32 + lq * 8);

    bf16x8 ones;
#pragma unroll
    for (int j = 0; j < 8; j++) ones[j] = (short)0x3F80;   // bf16 1.0

    // staging: chunk c <-> (key/dh = c&63, kgroup = c>>6)
    int c0 = t, c1 = t + 256;
    const ushort* Kg0 = Kp + (size_t)(c0 & 63) * DH + (c0 >> 6) * 8;
    const ushort* Kg1 = Kp + (size_t)(c1 & 63) * DH + (c1 >> 6) * 8;
    const ushort* Vg0 = Vp + (size_t)(c0 & 63) * S_ + (c0 >> 6) * 8;
    const ushort* Vg1 = Vp + (size_t)(c1 & 63) * S_ + (c1 >> 6) * 8;
    ushort* Kl0 = Kl + c0 * 8;
    ushort* Kl1 = Kl + c1 * 8;
    ushort* Vl0 = Vl + c0 * 8;
    ushort* Vl1 = Vl + c1 * 8;

    f32x4 o_acc[4];
    f32x4 l_acc = {0.f, 0.f, 0.f, 0.f};
#pragma unroll
    for (int nt = 0; nt < 4; nt++) o_acc[nt] = f32x4{0.f, 0.f, 0.f, 0.f};

    for (int kt = 0; kt < S_ / 64; kt++) {
        int kb = kt * 64;
        gload16(Kg0 + (size_t)kb * DH, Kl0);
        gload16(Kg1 + (size_t)kb * DH, Kl1);
        gload16(Vg0 + kb, Vl0);
        gload16(Vg1 + kb, Vl1);
        __syncthreads();           // sync_a: tile kt staged

        // ---- S^T = K·Q^T: 4 key-tiles of 16 (A=kf, B=qf) ----
        f32x4 sc[4];
#pragma unroll
        for (int nt = 0; nt < 4; nt++) {
            bf16x8 kf0 = *reinterpret_cast<const bf16x8*>(Kl + (lq * 64 + nt * 16 + ln) * 8);
            bf16x8 kf1 = *reinterpret_cast<const bf16x8*>(Kl + ((4 + lq) * 64 + nt * 16 + ln) * 8);
            f32x4 c = {0.f, 0.f, 0.f, 0.f};
            c = MFMA16(kf0, qf0, c);
            c = MFMA16(kf1, qf1, c);
            sc[nt] = c;
        }
        // ---- softmax: bare exp2, pack 4 consecutive keys -> one b64 write ----
#pragma unroll
        for (int nt = 0; nt < 4; nt++) {
            float p0 = EXP2(sc[nt][0]);
            float p1 = EXP2(sc[nt][1]);
            float p2 = EXP2(sc[nt][2]);
            float p3 = EXP2(sc[nt][3]);
            uint2v pk;
            pk.x = pkbf(p0, p1);
            pk.y = pkbf(p2, p3);
            *reinterpret_cast<uint2v*>(&Pl[w][ln * 72 + nt * 16 + lq * 4]) = pk;
        }
        bf16x8 pf0 = *reinterpret_cast<const bf16x8*>(&Pl[w][ln * 72 + lq * 8]);
        bf16x8 pf1 = *reinterpret_cast<const bf16x8*>(&Pl[w][ln * 72 + 32 + lq * 8]);
        // ---- l row-sum of truncated P (ones-column MFMA) ----
        l_acc = MFMA16(pf0, ones, l_acc);
        l_acc = MFMA16(pf1, ones, l_acc);
        // ---- PV: 4 dh-tiles, K=64 keys ----
#pragma unroll
        for (int nt = 0; nt < 4; nt++) {
            bf16x8 vf0 = *reinterpret_cast<const bf16x8*>(Vl + (lq * 64 + nt * 16 + ln) * 8);
            bf16x8 vf1 = *reinterpret_cast<const bf16x8*>(Vl + ((4 + lq) * 64 + nt * 16 + ln) * 8);
            o_acc[nt] = MFMA16(pf0, vf0, o_acc[nt]);
            o_acc[nt] = MFMA16(pf1, vf1, o_acc[nt]);
        }
        __syncthreads();           // sync_b: Kl/Vl reads done; next gloads safe
    }

    // ---- epilogue: l already per-row, no shuffles ----
    float linv[4];
#pragma unroll
    for (int r = 0; r < 4; r++) linv[r] = 1.0f / l_acc[r];
    int b = bh >> 4, h = bh & 15;
#pragma unroll
    for (int nt = 0; nt < 4; nt++)
#pragma unroll
        for (int r = 0; r < 4; r++) {
            int s = qt * 16 + lq * 4 + r;
            O[((b * S_ + s) * H_ + h) * DH + nt * 16 + ln] =
                f2bf(o_acc[nt][r] * linv[r]);
        }
}

// ---------------------------------------------------------------------------
extern "C" void kernel_launch(void* const* d_in, const int* in_sizes, int n_in,
                              void* d_out, int out_size, void* d_ws, size_t ws_size,
                              hipStream_t stream) {
    const float* x  = (const float*)d_in[0];
    const float* Wq = (const float*)d_in[1];
    const float* bq = (const float*)d_in[2];
    const float* Wk = (const float*)d_in[3];
    const float* bk = (const float*)d_in[4];
    const float* Wv = (const float*)d_in[5];
    const float* bv = (const float*)d_in[6];
    const float* Wo = (const float*)d_in[7];
    const float* bo = (const float*)d_in[8];
    float* out = (float*)d_out;

    char* ws = (char*)d_ws;
    const size_t MB = 1024 * 1024;
    ushort* wtq = (ushort*)(ws + 0 * MB);    // [3072,1024] fused q,k,v contiguous
    ushort* wtk = (ushort*)(ws + 2 * MB);
    ushort* wtv = (ushort*)(ws + 4 * MB);
    ushort* wto = (ushort*)(ws + 6 * MB);
    ushort* xb  = (ushort*)(ws + 8 * MB);    // bf16 x [M,K]
    ushort* Qb  = (ushort*)(ws + 16 * MB);   // [B,H,S,Dh] (pre-scaled by kQS)
    ushort* Kb  = (ushort*)(ws + 24 * MB);   // [B,H,S,Dh]
    ushort* Vtb = (ushort*)(ws + 32 * MB);   // [B,H,Dh,S]
    ushort* AO  = (ushort*)(ws + 40 * MB);   // [B,S,D] bf16

    // prep: 4 weight transposes (z=0..3) + x convert (z=4)
    prep5<<<dim3(32, 32, 5), dim3(32, 8), 0, stream>>>(
        x, Wq, Wk, Wv, Wo, xb, wtq, wtk, wtv, wto);

    // fused QKV projection: N = 3072, 128x128 tiles -> 768 blocks = 3/CU
    gemm128<0, 128><<<dim3(M_ / 128, 3072 / 128), 256, 0, stream>>>(
        xb, wtq, bq, bk, bv, Qb, Kb, Vtb, nullptr);

    // attention: 1024 blocks = 4 blocks/CU
    attn64t<<<32 * 32, 256, 0, stream>>>(Qb, Kb, Vtb, AO);

    // output projection: N = 1024, 128x64 tiles -> 512 blocks = 2/CU
    gemm128<1, 64><<<dim3(M_ / 128, D_ / 64), 256, 0, stream>>>(
        AO, wto, bo, nullptr, nullptr, nullptr, nullptr, nullptr, out);
}

// Round 14
// 198.800 us; speedup vs baseline: 1.0419x; 1.0419x over previous
//
#include <hip/hip_runtime.h>
#include <hip/hip_bf16.h>

typedef short bf16x8 __attribute__((ext_vector_type(8)));
typedef float f32x4 __attribute__((ext_vector_type(4)));
typedef unsigned uint2v __attribute__((ext_vector_type(2)));

#define MFMA16(a, b, c) __builtin_amdgcn_mfma_f32_16x16x32_bf16((a), (b), (c), 0, 0, 0)

#if __has_builtin(__builtin_amdgcn_exp2f)
#define EXP2(x) __builtin_amdgcn_exp2f(x)
#else
#define EXP2(x) exp2f(x)
#endif

static constexpr int B_ = 2, S_ = 2048, D_ = 1024, H_ = 16, DH = 64;
static constexpr int M_ = B_ * S_;   // 4096
static constexpr int K_ = D_;        // 1024
static constexpr float kQS = 0.18033688011112042f;   // log2(e)/8, folded into Wq

static __device__ __forceinline__ ushort f2bf(float f) {
    __hip_bfloat16 h = __float2bfloat16(f);
    return *reinterpret_cast<ushort*>(&h);
}
static __device__ __forceinline__ float bf2f(ushort u) {
    __hip_bfloat16 h;
    *reinterpret_cast<ushort*>(&h) = u;
    return __bfloat162float(h);
}

static __device__ __forceinline__ void gload16(const ushort* g, ushort* l) {
    __builtin_amdgcn_global_load_lds((const __attribute__((address_space(1))) void*)g,
                                     (__attribute__((address_space(3))) void*)l, 16, 0, 0);
}

// pack two fp32 -> (bf16(hi) << 16) | bf16(lo), truncation (v_perm_b32)
static __device__ __forceinline__ unsigned pkbf(float lo, float hi) {
    return __builtin_amdgcn_perm(__builtin_bit_cast(unsigned, hi),
                                 __builtin_bit_cast(unsigned, lo), 0x07060302u);
}

// ---------------------------------------------------------------------------
// Prep: z=0..3 -> fused convert+transpose of the 4 weights (Wq pre-scaled by
// log2(e)/8); z=4 -> fp32->bf16 convert of x (4M elems, 16/thread).
// ---------------------------------------------------------------------------
__global__ __launch_bounds__(256) void prep5(const float* __restrict__ x,
                                             const float* __restrict__ W0,
                                             const float* __restrict__ W1,
                                             const float* __restrict__ W2,
                                             const float* __restrict__ W3,
                                             ushort* __restrict__ xb,
                                             ushort* __restrict__ T0,
                                             ushort* __restrict__ T1,
                                             ushort* __restrict__ T2,
                                             ushort* __restrict__ T3) {
    int z = blockIdx.z;
    int tx = threadIdx.x, ty = threadIdx.y;
    int t = ty * 32 + tx;
    if (z == 4) {
        int blk = blockIdx.y * 32 + blockIdx.x;      // 0..1023
#pragma unroll
        for (int k = 0; k < 4; k++) {
            int i = blk * 1024 + k * 256 + t;        // float4 id
            float4 v = reinterpret_cast<const float4*>(x)[i];
            ushort4 o;
            o.x = f2bf(v.x); o.y = f2bf(v.y); o.z = f2bf(v.z); o.w = f2bf(v.w);
            reinterpret_cast<ushort4*>(xb)[i] = o;
        }
        return;
    }
    __shared__ float tile[32][33];
    const float* W = (z == 0) ? W0 : (z == 1) ? W1 : (z == 2) ? W2 : W3;
    ushort* T = (z == 0) ? T0 : (z == 1) ? T1 : (z == 2) ? T2 : T3;
    float sc = (z == 0) ? kQS : 1.0f;
    int bx = blockIdx.x, by = blockIdx.y;
#pragma unroll
    for (int i = 0; i < 4; i++)
        tile[ty + i * 8][tx] = W[(by * 32 + ty + i * 8) * D_ + bx * 32 + tx];
    __syncthreads();
#pragma unroll
    for (int i = 0; i < 4; i++)
        T[(bx * 32 + ty + i * 8) * K_ + by * 32 + tx] = f2bf(tile[tx][ty + i * 8] * sc);
}

// ---------------------------------------------------------------------------
// m97-style GEMM (single-buffered), swapped-operand epilogues (r13, neutral
// but kept: vector stores). MODE 0 (TN=128): fused QKV; MODE 1 (TN=64): O-proj.
// ---------------------------------------------------------------------------
template <int MODE, int TN>
__global__ __launch_bounds__(256, 3) void gemm128(const ushort* __restrict__ A,
                                                  const ushort* __restrict__ Wt,
                                                  const float* __restrict__ bias_q,
                                                  const float* __restrict__ bias_k,
                                                  const float* __restrict__ bias_v,
                                                  ushort* __restrict__ Qb,
                                                  ushort* __restrict__ Kb,
                                                  ushort* __restrict__ Vtb,
                                                  float* __restrict__ outf) {
    constexpr int NJ = TN / 32;
    __shared__ __align__(16) ushort As[128 * 32];
    __shared__ __align__(16) ushort Bs[TN * 32];

    int m0 = blockIdx.x * 128;
    int n0 = blockIdx.y * TN;
    int t = threadIdx.x;
    int lane = t & 63, w = t >> 6;
    int ln = lane & 15, lq = lane >> 4;
    int wm = (w >> 1) * 64, wn = (w & 1) * (TN / 2);

    int c0 = t, c1 = t + 256;
    const ushort* Ag0 = A + (size_t)(m0 + (c0 >> 2)) * K_ + (c0 & 3) * 8;
    const ushort* Ag1 = A + (size_t)(m0 + (c1 >> 2)) * K_ + (c1 & 3) * 8;
    const ushort* Bg0 = Wt + (size_t)(n0 + (c0 >> 2)) * K_ + (c0 & 3) * 8;
    const ushort* Bg1 = Wt + (size_t)(n0 + (c1 >> 2)) * K_ + (c1 & 3) * 8;
    ushort* Al0 = As + c0 * 8;
    ushort* Al1 = As + c1 * 8;
    ushort* Bl0 = Bs + c0 * 8;
    ushort* Bl1 = Bs + c1 * 8;

    const bool swp = (MODE == 1) || (n0 < 2048);   // block-uniform

    f32x4 acc[4][NJ];
#pragma unroll
    for (int i = 0; i < 4; i++)
#pragma unroll
        for (int j = 0; j < NJ; j++) acc[i][j] = f32x4{0.f, 0.f, 0.f, 0.f};

    if (swp) {
        for (int k0 = 0; k0 < K_; k0 += 32) {
            gload16(Ag0 + k0, Al0);
            gload16(Ag1 + k0, Al1);
            gload16(Bg0 + k0, Bl0);
            if (TN == 128) gload16(Bg1 + k0, Bl1);
            __syncthreads();
            bf16x8 af[4], bfr[NJ];
#pragma unroll
            for (int i = 0; i < 4; i++)
                af[i] = *reinterpret_cast<const bf16x8*>(As + (wm + i * 16 + ln) * 32 + lq * 8);
#pragma unroll
            for (int j = 0; j < NJ; j++)
                bfr[j] = *reinterpret_cast<const bf16x8*>(Bs + (wn + j * 16 + ln) * 32 + lq * 8);
#pragma unroll
            for (int i = 0; i < 4; i++)
#pragma unroll
                for (int j = 0; j < NJ; j++)
                    acc[i][j] = MFMA16(bfr[j], af[i], acc[i][j]);   // swapped
            __syncthreads();
        }
    } else {
        for (int k0 = 0; k0 < K_; k0 += 32) {
            gload16(Ag0 + k0, Al0);
            gload16(Ag1 + k0, Al1);
            gload16(Bg0 + k0, Bl0);
            if (TN == 128) gload16(Bg1 + k0, Bl1);
            __syncthreads();
            bf16x8 af[4], bfr[NJ];
#pragma unroll
            for (int i = 0; i < 4; i++)
                af[i] = *reinterpret_cast<const bf16x8*>(As + (wm + i * 16 + ln) * 32 + lq * 8);
#pragma unroll
            for (int j = 0; j < NJ; j++)
                bfr[j] = *reinterpret_cast<const bf16x8*>(Bs + (wn + j * 16 + ln) * 32 + lq * 8);
#pragma unroll
            for (int i = 0; i < 4; i++)
#pragma unroll
                for (int j = 0; j < NJ; j++)
                    acc[i][j] = MFMA16(af[i], bfr[j], acc[i][j]);
            __syncthreads();
        }
    }

    if (MODE == 1) {
#pragma unroll
        for (int j = 0; j < NJ; j++) {
            int nb = n0 + wn + j * 16 + lq * 4;
            float4 bv4 = *reinterpret_cast<const float4*>(bias_q + nb);
#pragma unroll
            for (int i = 0; i < 4; i++) {
                int m = m0 + wm + i * 16 + ln;
                float4 o;
                o.x = acc[i][j][0] + bv4.x;
                o.y = acc[i][j][1] + bv4.y;
                o.z = acc[i][j][2] + bv4.z;
                o.w = acc[i][j][3] + bv4.w;
                *reinterpret_cast<float4*>(outf + (size_t)m * D_ + nb) = o;
            }
        }
    } else if (n0 < 2048) {
        int which = n0 >> 10;
        const float* bp = which ? bias_k : bias_q;
        ushort* dst = which ? Kb : Qb;
        float bsc = which ? 1.0f : kQS;
#pragma unroll
        for (int j = 0; j < NJ; j++) {
            int nb = ((n0 + wn + j * 16) & 1023) + lq * 4;
            int h = nb >> 6, dhb = nb & 63;
            float4 bv4 = *reinterpret_cast<const float4*>(bp + nb);
            bv4.x *= bsc; bv4.y *= bsc; bv4.z *= bsc; bv4.w *= bsc;
#pragma unroll
            for (int i = 0; i < 4; i++) {
                int m = m0 + wm + i * 16 + ln;
                int b = m >> 11, s = m & 2047;
                ushort4 o4;
                o4.x = f2bf(acc[i][j][0] + bv4.x);
                o4.y = f2bf(acc[i][j][1] + bv4.y);
                o4.z = f2bf(acc[i][j][2] + bv4.z);
                o4.w = f2bf(acc[i][j][3] + bv4.w);
                *reinterpret_cast<ushort4*>(dst + (((size_t)(b * H_ + h) * S_) + s) * DH + dhb) = o4;
            }
        }
    } else {
#pragma unroll
        for (int j = 0; j < NJ; j++) {
            int n = n0 + wn + j * 16 + ln;
            int nn = n & 1023, h = nn >> 6, dh = nn & 63;
            float bv = bias_v[nn];
#pragma unroll
            for (int i = 0; i < 4; i++) {
                int m = m0 + wm + i * 16 + lq * 4;
                int b = m >> 11, s0 = m & 2047;
                ushort4 o4;
                o4.x = f2bf(acc[i][j][0] + bv);
                o4.y = f2bf(acc[i][j][1] + bv);
                o4.z = f2bf(acc[i][j][2] + bv);
                o4.w = f2bf(acc[i][j][3] + bv);
                *reinterpret_cast<ushort4*>(Vtb + (((size_t)(b * H_ + h) * DH) + dh) * S_ + s0) = o4;
            }
        }
    }
}

// ---------------------------------------------------------------------------
// Flash attention v8: K-SPLIT x2 + 2 q-tiles/wave. Grid = 1024 blocks
// (half, bh, 16 q-blocks of 128 rows), 4 waves x 32 q-rows, 16 kt-iters of
// 64 keys. LDS = 8(K)+8(V)+18(P) = 34 KB -> 4 blocks/CU, 16 waves/CU kept.
// K/V fragment reads (192 of 248 LDS-cyc/iter in r11) are now SHARED across
// 2 q-tiles: 304 LDS-cyc per 36 MFMA vs 248 per 18 -> 1.6x LDS intensity;
// LDS floor 127k -> 78k cyc/CU (r10/r11: LDS pipe is the attn bottleneck).
// r11 P-path kept: swapped QK (S^T=K.Q^T), b64 P-writes, ones-MFMA l.
// Halves write normalized bf16 O-partials + fp32 l; attn_comb (r8) merges.
// ---------------------------------------------------------------------------
__global__ __launch_bounds__(256, 4) void attn128s(const ushort* __restrict__ Q,
                                                   const ushort* __restrict__ K,
                                                   const ushort* __restrict__ Vt,
                                                   ushort* __restrict__ O1,
                                                   ushort* __restrict__ O2,
                                                   float* __restrict__ L) {
    __shared__ __align__(16) ushort Kl[512 * 8];         // 8 KB
    __shared__ __align__(16) ushort Vl[512 * 8];         // 8 KB
    __shared__ __align__(16) ushort Pl[4][2][16 * 72];   // 18 KB

    int bid = blockIdx.x;
    int half = bid >> 9;        // K-half
    int rem = bid & 511;
    int qb = rem & 15;          // 16 q-blocks of 128 rows
    int bh = rem >> 4;          // b*H + h
    int t = threadIdx.x;
    int lane = t & 63, w = t >> 6;
    int ln = lane & 15, lq = lane >> 4;
    int q0 = qb * 128 + w * 32;

    const ushort* Qp = Q + (size_t)bh * S_ * DH;
    const ushort* Kp = K + (size_t)bh * S_ * DH + (size_t)half * 1024 * DH;
    const ushort* Vp = Vt + (size_t)bh * DH * S_ + (size_t)half * 1024;

    bf16x8 qf[2][2];
#pragma unroll
    for (int tl = 0; tl < 2; tl++) {
        const ushort* qp = Qp + (q0 + tl * 16 + ln) * DH + lq * 8;
        qf[tl][0] = *reinterpret_cast<const bf16x8*>(qp);
        qf[tl][1] = *reinterpret_cast<const bf16x8*>(qp + 32);
    }

    bf16x8 ones;
#pragma unroll
    for (int j = 0; j < 8; j++) ones[j] = (short)0x3F80;   // bf16 1.0

    // staging: chunk c <-> (key/dh = c&63, kgroup = c>>6)
    int c0 = t, c1 = t + 256;
    const ushort* Kg0 = Kp + (size_t)(c0 & 63) * DH + (c0 >> 6) * 8;
    const ushort* Kg1 = Kp + (size_t)(c1 & 63) * DH + (c1 >> 6) * 8;
    const ushort* Vg0 = Vp + (size_t)(c0 & 63) * S_ + (c0 >> 6) * 8;
    const ushort* Vg1 = Vp + (size_t)(c1 & 63) * S_ + (c1 >> 6) * 8;
    ushort* Kl0 = Kl + c0 * 8;
    ushort* Kl1 = Kl + c1 * 8;
    ushort* Vl0 = Vl + c0 * 8;
    ushort* Vl1 = Vl + c1 * 8;

    f32x4 o_acc[2][4];
    f32x4 l_acc[2];
#pragma unroll
    for (int tl = 0; tl < 2; tl++) {
        l_acc[tl] = f32x4{0.f, 0.f, 0.f, 0.f};
#pragma unroll
        for (int nt = 0; nt < 4; nt++) o_acc[tl][nt] = f32x4{0.f, 0.f, 0.f, 0.f};
    }

    for (int kt = 0; kt < 16; kt++) {
        int kb = kt * 64;
        gload16(Kg0 + (size_t)kb * DH, Kl0);
        gload16(Kg1 + (size_t)kb * DH, Kl1);
        gload16(Vg0 + kb, Vl0);
        gload16(Vg1 + kb, Vl1);
        __syncthreads();           // sync_a: tile kt staged

        // ---- S^T = K·Q^T: 4 key-tiles x 2 q-tiles; K-frags read ONCE ----
        f32x4 sc[2][4];
#pragma unroll
        for (int nt = 0; nt < 4; nt++) {
            bf16x8 kf0 = *reinterpret_cast<const bf16x8*>(Kl + (lq * 64 + nt * 16 + ln) * 8);
            bf16x8 kf1 = *reinterpret_cast<const bf16x8*>(Kl + ((4 + lq) * 64 + nt * 16 + ln) * 8);
#pragma unroll
            for (int tl = 0; tl < 2; tl++) {
                f32x4 c = {0.f, 0.f, 0.f, 0.f};
                c = MFMA16(kf0, qf[tl][0], c);
                c = MFMA16(kf1, qf[tl][1], c);
                sc[tl][nt] = c;
            }
        }
        // ---- softmax: bare exp2, b64 P-writes (wave-private) ----
#pragma unroll
        for (int tl = 0; tl < 2; tl++)
#pragma unroll
            for (int nt = 0; nt < 4; nt++) {
                float p0 = EXP2(sc[tl][nt][0]);
                float p1 = EXP2(sc[tl][nt][1]);
                float p2 = EXP2(sc[tl][nt][2]);
                float p3 = EXP2(sc[tl][nt][3]);
                uint2v pk;
                pk.x = pkbf(p0, p1);
                pk.y = pkbf(p2, p3);
                *reinterpret_cast<uint2v*>(&Pl[w][tl][ln * 72 + nt * 16 + lq * 4]) = pk;
            }
        bf16x8 pf[2][2];
#pragma unroll
        for (int tl = 0; tl < 2; tl++) {
            pf[tl][0] = *reinterpret_cast<const bf16x8*>(&Pl[w][tl][ln * 72 + lq * 8]);
            pf[tl][1] = *reinterpret_cast<const bf16x8*>(&Pl[w][tl][ln * 72 + 32 + lq * 8]);
            // l row-sum of truncated P
            l_acc[tl] = MFMA16(pf[tl][0], ones, l_acc[tl]);
            l_acc[tl] = MFMA16(pf[tl][1], ones, l_acc[tl]);
        }
        // ---- PV: V-frags read ONCE, used for both q-tiles ----
#pragma unroll
        for (int nt = 0; nt < 4; nt++) {
            bf16x8 vf0 = *reinterpret_cast<const bf16x8*>(Vl + (lq * 64 + nt * 16 + ln) * 8);
            bf16x8 vf1 = *reinterpret_cast<const bf16x8*>(Vl + ((4 + lq) * 64 + nt * 16 + ln) * 8);
#pragma unroll
            for (int tl = 0; tl < 2; tl++) {
                o_acc[tl][nt] = MFMA16(pf[tl][0], vf0, o_acc[tl][nt]);
                o_acc[tl][nt] = MFMA16(pf[tl][1], vf1, o_acc[tl][nt]);
            }
        }
        __syncthreads();           // sync_b: Kl/Vl reads done; next gloads safe
    }

    // ---- epilogue: normalized partial + l ----
    ushort* Op = half ? O2 : O1;
    float* Lp = L + ((size_t)half * 32 + bh) * S_;
    int b = bh >> 4, h = bh & 15;
#pragma unroll
    for (int tl = 0; tl < 2; tl++) {
        float linv[4];
#pragma unroll
        for (int r = 0; r < 4; r++) {
            linv[r] = 1.0f / l_acc[tl][r];
            if (ln == 0) Lp[q0 + tl * 16 + lq * 4 + r] = l_acc[tl][r];
        }
#pragma unroll
        for (int nt = 0; nt < 4; nt++)
#pragma unroll
            for (int r = 0; r < 4; r++) {
                int s = q0 + tl * 16 + lq * 4 + r;
                Op[((b * S_ + s) * H_ + h) * DH + nt * 16 + ln] =
                    f2bf(o_acc[tl][nt][r] * linv[r]);
            }
    }
}

// ---------------------------------------------------------------------------
// Combine the two K-half partials: AO = (l1*O1n + l2*O2n)/(l1+l2), bf16.
// ---------------------------------------------------------------------------
__global__ __launch_bounds__(256) void attn_comb(const ushort* __restrict__ O1,
                                                 const ushort* __restrict__ O2,
                                                 const float* __restrict__ L,
                                                 ushort* __restrict__ AO) {
    int i = blockIdx.x * 256 + threadIdx.x;    // 8-elem group id
    int row = i >> 7;           // (b*S+s)
    int col = (i & 127) * 8;
    int h = col >> 6;
    int b = row >> 11, s = row & 2047;
    int bh = b * 16 + h;
    float l1 = L[(size_t)bh * S_ + s];
    float l2 = L[((size_t)32 + bh) * S_ + s];
    float inv = 1.0f / (l1 + l2);
    float w1 = l1 * inv, w2 = l2 * inv;
    size_t off = (size_t)row * D_ + col;
    ushort4 a0 = reinterpret_cast<const ushort4*>(O1 + off)[0];
    ushort4 a1 = reinterpret_cast<const ushort4*>(O1 + off)[1];
    ushort4 b0 = reinterpret_cast<const ushort4*>(O2 + off)[0];
    ushort4 b1 = reinterpret_cast<const ushort4*>(O2 + off)[1];
    ushort4 o0, o1v;
    o0.x = f2bf(w1 * bf2f(a0.x) + w2 * bf2f(b0.x));
    o0.y = f2bf(w1 * bf2f(a0.y) + w2 * bf2f(b0.y));
    o0.z = f2bf(w1 * bf2f(a0.z) + w2 * bf2f(b0.z));
    o0.w = f2bf(w1 * bf2f(a0.w) + w2 * bf2f(b0.w));
    o1v.x = f2bf(w1 * bf2f(a1.x) + w2 * bf2f(b1.x));
    o1v.y = f2bf(w1 * bf2f(a1.y) + w2 * bf2f(b1.y));
    o1v.z = f2bf(w1 * bf2f(a1.z) + w2 * bf2f(b1.z));
    o1v.w = f2bf(w1 * bf2f(a1.w) + w2 * bf2f(b1.w));
    reinterpret_cast<ushort4*>(AO + off)[0] = o0;
    reinterpret_cast<ushort4*>(AO + off)[1] = o1v;
}

// ---------------------------------------------------------------------------
extern "C" void kernel_launch(void* const* d_in, const int* in_sizes, int n_in,
                              void* d_out, int out_size, void* d_ws, size_t ws_size,
                              hipStream_t stream) {
    const float* x  = (const float*)d_in[0];
    const float* Wq = (const float*)d_in[1];
    const float* bq = (const float*)d_in[2];
    const float* Wk = (const float*)d_in[3];
    const float* bk = (const float*)d_in[4];
    const float* Wv = (const float*)d_in[5];
    const float* bv = (const float*)d_in[6];
    const float* Wo = (const float*)d_in[7];
    const float* bo = (const float*)d_in[8];
    float* out = (float*)d_out;

    char* ws = (char*)d_ws;
    const size_t MB = 1024 * 1024;
    ushort* wtq = (ushort*)(ws + 0 * MB);    // [3072,1024] fused q,k,v contiguous
    ushort* wtk = (ushort*)(ws + 2 * MB);
    ushort* wtv = (ushort*)(ws + 4 * MB);
    ushort* wto = (ushort*)(ws + 6 * MB);
    ushort* xb  = (ushort*)(ws + 8 * MB);    // bf16 x [M,K]; dead after QKV
    ushort* Qb  = (ushort*)(ws + 16 * MB);   // [B,H,S,Dh] (pre-scaled by kQS)
    ushort* Kb  = (ushort*)(ws + 24 * MB);   // [B,H,S,Dh]
    ushort* Vtb = (ushort*)(ws + 32 * MB);   // [B,H,Dh,S]
    ushort* AO  = (ushort*)(ws + 40 * MB);   // [B,S,D] bf16
    ushort* O1  = (ushort*)(ws + 8 * MB);    // half-0 partial (reuses xb)
    ushort* O2  = (ushort*)(ws + 48 * MB);   // half-1 partial
    float*  Lw  = (float*)(ws + 56 * MB);    // l partials [2][32][S]

    // prep: 4 weight transposes (z=0..3) + x convert (z=4)
    prep5<<<dim3(32, 32, 5), dim3(32, 8), 0, stream>>>(
        x, Wq, Wk, Wv, Wo, xb, wtq, wtk, wtv, wto);

    // fused QKV projection: N = 3072, 128x128 tiles -> 768 blocks = 3/CU
    gemm128<0, 128><<<dim3(M_ / 128, 3072 / 128), 256, 0, stream>>>(
        xb, wtq, bq, bk, bv, Qb, Kb, Vtb, nullptr);

    // attention: K-split x2, 2 q-tiles/wave; 1024 blocks = 4/CU, 16 waves/CU
    attn128s<<<1024, 256, 0, stream>>>(Qb, Kb, Vtb, O1, O2, Lw);
    attn_comb<<<(M_ * D_ / 8) / 256, 256, 0, stream>>>(O1, O2, Lw, AO);

    // output projection: N = 1024, 128x64 tiles -> 512 blocks = 2/CU
    gemm128<1, 64><<<dim3(M_ / 128, D_ / 64), 256, 0, stream>>>(
        AO, wto, bo, nullptr, nullptr, nullptr, nullptr, nullptr, out);
}